// Round 7
// baseline (166.793 us; speedup 1.0000x reference)
//
#include <hip/hip_runtime.h>

// grid [2,160,160,160,3] fp32; interior outputs (i,j,k) in 2..157 per axis.
//
// R7: barrier-free register-pipelined x-march, NO LDS.
// Wave layout (from R6): lane = 16 y-rows (r = lane&15, DPP row) x 4 z-quads.
// Each lane loads its OWN row's 24-float z-window per slice directly from
// global (6 x global_load_dwordx4, L2/L3-served), double-buffered in regs
// (wA/wB parity); y-neighbors come from v_mov_dpp row_shr/shl (VALU pipe):
//   dy  = shr1(x) - shl1(x)       hyy = shr2(x) - 2x + shl2(x)
//   hyz = shr1(dz) - shl1(dz)
// x-terms keep the verified parity-bank pipeline (hxy/hxz from dy/dz two
// steps back, hxx from v0 four steps back).
// Rationale (R1/R5/R6 counters): DS busy ~12us, VALU ~13us, but kernel ~50us
// -> ~70% barrier/latency stall; every x-step ended in __syncthreads() gated
// on that step's loads. Removing LDS removes every barrier: waves fully
// independent, ~4056 waves ~= chip capacity resident, latency hidden by TLP.
#define OY 480                    // floats per y-row (160 z * 3 comps)
#define OX 76800                  // floats per x-slice
#define SB 12288000               // floats per batch
#define IT 12                     // output slices (x) per block; 13 segs
#define NSEG 13
#define NBLK 1014                 // 2 * 13(jt) * 3(zt) * 13(is)
#define INV_SIZE (1.0f/22778496.0f)  // 2*156^3*3

#define ROW_SHL1 0x101
#define ROW_SHL2 0x102
#define ROW_SHR1 0x111
#define ROW_SHR2 0x112

template<int CTRL>
__device__ __forceinline__ float dppf(float x){
    return __int_as_float(__builtin_amdgcn_update_dpp(
        0, __float_as_int(x), CTRL, 0xF, 0xF, true));
}

__device__ __forceinline__ float4 ld4p(const float* p){ return *reinterpret_cast<const float4*>(p); }

// One x-step at compile-time parity P. Computes slice x = i0-2+s from window
// bank WC; prefetches slice x+1 into bank WN (used next step). All branches
// on s are wave-uniform; DPP sits outside per-lane (vr) branches so halo-row
// lanes stay active as DPP sources.
#define STEP(P, V0a, V0b, DP, WC, WN) { \
    const int s = 2*d + (P); \
    if (qact) { \
        if (s <= 14) { \
            WN[0]=ld4p(nx);    WN[1]=ld4p(nx+4);  WN[2]=ld4p(nx+8); \
            WN[3]=ld4p(nx+12); WN[4]=ld4p(nx+16); WN[5]=ld4p(nx+20); \
            nx += OX; \
        } \
        float x[24]; \
        _Pragma("unroll") for (int q=0;q<6;++q){ \
            x[4*q]=WC[q].x; x[4*q+1]=WC[q].y; x[4*q+2]=WC[q].z; x[4*q+3]=WC[q].w; } \
        float dz0[4], dz1[4], dz2[4], dy0[4], dy1[4], v0c[4]; \
        _Pragma("unroll") for (int v=0; v<4; ++v) { \
            v0c[v] = x[3*v+6]; \
            dz0[v] = x[3*v+9]  - x[3*v+3]; \
            dz1[v] = x[3*v+10] - x[3*v+4]; \
            dz2[v] = x[3*v+11] - x[3*v+5]; \
            dy0[v] = dppf<ROW_SHR1>(x[3*v+6]) - dppf<ROW_SHL1>(x[3*v+6]); \
            dy1[v] = dppf<ROW_SHR1>(x[3*v+7]) - dppf<ROW_SHL1>(x[3*v+7]); \
        } \
        if (s >= 2 && s <= 13) { \
            _Pragma("unroll") for (int v=0; v<4; ++v) { \
                float c0 = x[3*v+6], c1 = x[3*v+7]; \
                float hy0 = dppf<ROW_SHR2>(c0) - 2.f*c0 + dppf<ROW_SHL2>(c0); \
                float hy1 = dppf<ROW_SHR2>(c1) - 2.f*c1 + dppf<ROW_SHL2>(c1); \
                float yz0 = dppf<ROW_SHR1>(dz0[v]) - dppf<ROW_SHL1>(dz0[v]); \
                float yz1 = dppf<ROW_SHR1>(dz1[v]) - dppf<ROW_SHL1>(dz1[v]); \
                float yz2 = dppf<ROW_SHR1>(dz2[v]) - dppf<ROW_SHL1>(dz2[v]); \
                if (vr) { \
                    float zz0 = x[3*v+12] - 2.f*x[3*v+6] + x[3*v]; \
                    float zz1 = x[3*v+13] - 2.f*x[3*v+7] + x[3*v+1]; \
                    float zz2 = x[3*v+14] - 2.f*x[3*v+8] + x[3*v+2]; \
                    cls2 = fmaf(zz0,zz0,cls2); cls2 = fmaf(zz1,zz1,cls2); cls1 = fmaf(zz2,zz2,cls1); \
                    cls2 = fmaf(hy0,hy0,cls2); cls1 = fmaf(hy1,hy1,cls1); \
                    cls4 = fmaf(yz0,yz0,cls4); cls3 = fmaf(yz1,yz1,cls3); cls1 = fmaf(yz2,yz2,cls1); \
                } \
            } \
        } \
        const bool eXY = vr && (s >= 3) && (s <= 14); \
        const bool eXX = vr && (s >= 4); \
        _Pragma("unroll") for (int v=0; v<4; ++v) { \
            if (eXY) { float h; \
                h = dy0[v] - DP[0][v]; cls3 = fmaf(h,h,cls3); \
                h = dy1[v] - DP[1][v]; cls1 = fmaf(h,h,cls1); \
                h = dz0[v] - DP[2][v]; cls3 = fmaf(h,h,cls3); \
                h = dz1[v] - DP[3][v]; cls2 = fmaf(h,h,cls2); \
                h = dz2[v] - DP[4][v]; cls1 = fmaf(h,h,cls1); \
            } \
            DP[0][v] = dy0[v]; DP[1][v] = dy1[v]; \
            DP[2][v] = dz0[v]; DP[3][v] = dz1[v]; DP[4][v] = dz2[v]; \
            if (eXX) { float h = v0c[v] - 2.f*V0a[v] + V0b[v]; cls1 = fmaf(h,h,cls1); } \
            V0b[v] = V0a[v]; V0a[v] = v0c[v]; \
        } \
    } \
}

__global__ __launch_bounds__(256)
void be_partials(const float* __restrict__ g, float* __restrict__ partial) {
    __shared__ float wsum[4];

    const int tid = threadIdx.x;
    const int bid = blockIdx.x;
    const int is = bid % NSEG;
    int r1 = bid / NSEG;
    const int zt = r1 % 3;  r1 /= 3;
    const int jt = r1 % 13;
    const int bb = r1 / 13;

    const int j0  = 2 + jt*12;     // output rows j0..j0+11 (windows j0-2..j0+13)
    const int zlo = 64*zt;         // z-window base for this tile
    const int i0  = 2 + is*IT;     // output slices i0..i0+11
    const float* __restrict__ G = g + (size_t)bb*SB + (size_t)(j0-2)*OY + 3*zlo;

    // ---- lane mapping: r = y-row (0..15, DPP row), Q = z-quad (0..15) ----
    const int r = tid & 15;
    const int Q = tid >> 4;
    const int qmax = (zt == 2) ? 7 : 16;       // zt=2 covers out z 130..157
    const bool qact = Q < qmax;
    const bool vr = (r >= 2) && (r <= 13);     // output rows
    // own-row 24-float window: floats 3*zlo + 12Q .. +23  (outputs z=zlo+4Q+2..5)
    const float* lane0 = G + (size_t)r*OY + 12*Q;
    const float* nx = lane0 + (size_t)(i0-1)*OX;   // first prefetch target

    // window banks (parity double buffer) + x-pipeline state
    float4 wA[6], wB[6];
    float v0A0[4], v0A1[4], v0B0[4], v0B1[4];
    float dpA[5][4], dpB[5][4];
    #pragma unroll
    for (int v=0; v<4; ++v) {
        v0A0[v]=v0A1[v]=v0B0[v]=v0B1[v]=0.f;
        #pragma unroll
        for (int q=0; q<5; ++q) { dpA[q][v]=0.f; dpB[q][v]=0.f; }
    }
    float cls1=0.f, cls2=0.f, cls3=0.f, cls4=0.f;

    // warmup: slice x = i0-2 into bank A
    if (qact) {
        const float* wp = lane0 + (size_t)(i0-2)*OX;
        wA[0]=ld4p(wp);    wA[1]=ld4p(wp+4);  wA[2]=ld4p(wp+8);
        wA[3]=ld4p(wp+12); wA[4]=ld4p(wp+16); wA[5]=ld4p(wp+20);
    }

    #pragma unroll 1
    for (int d = 0; d < 8; ++d) {
        STEP(0, v0A0, v0A1, dpA, wA, wB)
        STEP(1, v0B0, v0B1, dpB, wB, wA)
    }

    // fold weight classes (term multiplicities 1,2,3,4; 0.0625 = (0.25)^2)
    float sv = fmaf(2.f, cls2, cls1);
    sv = fmaf(3.f, cls3, sv);
    sv = fmaf(4.f, cls4, sv);
    sv *= 0.0625f;

    #pragma unroll
    for (int off = 32; off > 0; off >>= 1) sv += __shfl_down(sv, off, 64);
    if ((tid & 63) == 0) wsum[tid >> 6] = sv;
    __syncthreads();
    if (tid == 0)
        partial[bid] = (wsum[0] + wsum[1]) + (wsum[2] + wsum[3]);
}

__global__ __launch_bounds__(256)
void be_final(const float* __restrict__ partial, float* __restrict__ out) {
    float s = 0.0f;
    for (int i = threadIdx.x; i < NBLK; i += 256) s += partial[i];
    #pragma unroll
    for (int off = 32; off > 0; off >>= 1) s += __shfl_down(s, off, 64);
    __shared__ float ws[4];
    if ((threadIdx.x & 63) == 0) ws[threadIdx.x >> 6] = s;
    __syncthreads();
    if (threadIdx.x == 0)
        out[0] = ((ws[0] + ws[1]) + (ws[2] + ws[3])) * INV_SIZE;
}

extern "C" void kernel_launch(void* const* d_in, const int* in_sizes, int n_in,
                              void* d_out, int out_size, void* d_ws, size_t ws_size,
                              hipStream_t stream) {
    const float* grid = (const float*)d_in[0];
    float* out = (float*)d_out;
    float* partials = (float*)d_ws;    // 1014 floats

    be_partials<<<dim3(NBLK), dim3(256), 0, stream>>>(grid, partials);
    be_final<<<1, 256, 0, stream>>>(partials, out);
}

// Round 8
// 156.131 us; speedup vs baseline: 1.0683x; 1.0683x over previous
//
#include <hip/hip_runtime.h>

// grid [2,160,160,160,3] fp32; interior outputs (i,j,k) in 2..157 per axis.
//
// R8: single-wave blocks, zero barriers, wave-private LDS ring.
// Block = 1 wave = 16 y-rows (r = lane&15, DPP rows) x 4 z-quads (Q).
// Each wave owns a 3-slice LDS ring (16 rows x 60 floats = full z-window
// incl. halo). March x with a 2-deep register staging pipeline:
//   step S: issue slice S+2 -> reg bank | compute ring[S%3] | write bank
//           (slice S+1, loaded a full step ago) -> ring[(S+1)%3]
// No __syncthreads anywhere: intra-wave LDS RAW is ordered (DS pipe is
// in-order per wave), so the compiler emits COUNTED vmcnt/lgkmcnt from data
// deps only -- staging loads stay in flight across steps (the thing
// __syncthreads' implicit vmcnt(0) drain made impossible in R1-R6).
// y-stencil via DPP row_shr/shl (R6, verified); x-terms via the verified
// parity-bank register pipeline. 16 steps fully unrolled (S literal ->
// all step-window conditions fold at compile time).
#define OY 480                    // floats per y-row (160 z * 3 comps)
#define OX 76800                  // floats per x-slice
#define SB 12288000               // floats per batch
#define RST 60                    // LDS row stride (floats); 60%32=28 -> 2-way max
#define SLC 960                   // floats per slice (16 rows * 60)
#define IT 12                     // output slices (x) per wave; 13 segs
#define NSEG 13
#define NBLK 3380                 // 2 * 13(jt) * 10(zt) * 13(is)
#define INV_SIZE (1.0f/22778496.0f)  // 2*156^3*3

#define ROW_SHL1 0x101
#define ROW_SHL2 0x102
#define ROW_SHR1 0x111
#define ROW_SHR2 0x112

template<int CTRL>
__device__ __forceinline__ float dppf(float x){
    return __int_as_float(__builtin_amdgcn_update_dpp(
        0, __float_as_int(x), CTRL, 0xF, 0xF, true));
}

__device__ __forceinline__ float4 ld4p(const float* p){ return *reinterpret_cast<const float4*>(p); }
__device__ __forceinline__ void st4p(float* p, float4 v){ *reinterpret_cast<float4*>(p) = v; }

// One x-step, S is a LITERAL constant. SBc holds slice S+1 (write to ring);
// SBn receives slice S+2. DPP sits under wave-uniform-per-row qact only;
// per-lane vr gates accumulation exclusively.
#define STEPX(S, V0a, V0b, DP, SBc, SBn) { \
    if ((S) <= 13) { \
        const float* bp = Gs + (size_t)((S)+2)*OX; \
        SBn[0]=ld4p(bp+gof0); SBn[1]=ld4p(bp+gof1); SBn[2]=ld4p(bp+gof2); \
        if (wv3) SBn[3]=ld4p(bp+gof3); \
    } \
    if (qact) { \
        const float* Lr = lds + ((S)%3)*SLC + oj; \
        float x[24]; \
        { float4 y0=ld4p(Lr),y1=ld4p(Lr+4),y2=ld4p(Lr+8),y3=ld4p(Lr+12),y4=ld4p(Lr+16),y5=ld4p(Lr+20); \
          x[0]=y0.x;x[1]=y0.y;x[2]=y0.z;x[3]=y0.w; x[4]=y1.x;x[5]=y1.y;x[6]=y1.z;x[7]=y1.w; \
          x[8]=y2.x;x[9]=y2.y;x[10]=y2.z;x[11]=y2.w; x[12]=y3.x;x[13]=y3.y;x[14]=y3.z;x[15]=y3.w; \
          x[16]=y4.x;x[17]=y4.y;x[18]=y4.z;x[19]=y4.w; x[20]=y5.x;x[21]=y5.y;x[22]=y5.z;x[23]=y5.w; } \
        float dz0[4],dz1[4],dz2[4],dy0[4],dy1[4],v0c[4]; \
        _Pragma("unroll") for (int v=0; v<4; ++v) { \
            v0c[v] = x[3*v+6]; \
            dz0[v] = x[3*v+9]-x[3*v+3]; dz1[v]=x[3*v+10]-x[3*v+4]; dz2[v]=x[3*v+11]-x[3*v+5]; \
            dy0[v] = dppf<ROW_SHR1>(x[3*v+6]) - dppf<ROW_SHL1>(x[3*v+6]); \
            dy1[v] = dppf<ROW_SHR1>(x[3*v+7]) - dppf<ROW_SHL1>(x[3*v+7]); \
        } \
        if ((S) >= 2 && (S) <= 13) { \
            _Pragma("unroll") for (int v=0; v<4; ++v) { \
                float c0=x[3*v+6], c1=x[3*v+7]; \
                float hy0 = dppf<ROW_SHR2>(c0) - 2.f*c0 + dppf<ROW_SHL2>(c0); \
                float hy1 = dppf<ROW_SHR2>(c1) - 2.f*c1 + dppf<ROW_SHL2>(c1); \
                float yz0 = dppf<ROW_SHR1>(dz0[v]) - dppf<ROW_SHL1>(dz0[v]); \
                float yz1 = dppf<ROW_SHR1>(dz1[v]) - dppf<ROW_SHL1>(dz1[v]); \
                float yz2 = dppf<ROW_SHR1>(dz2[v]) - dppf<ROW_SHL1>(dz2[v]); \
                if (vr) { \
                    float zz0 = x[3*v+12]-2.f*x[3*v+6]+x[3*v]; \
                    float zz1 = x[3*v+13]-2.f*x[3*v+7]+x[3*v+1]; \
                    float zz2 = x[3*v+14]-2.f*x[3*v+8]+x[3*v+2]; \
                    cls2=fmaf(zz0,zz0,cls2); cls2=fmaf(zz1,zz1,cls2); cls1=fmaf(zz2,zz2,cls1); \
                    cls2=fmaf(hy0,hy0,cls2); cls1=fmaf(hy1,hy1,cls1); \
                    cls4=fmaf(yz0,yz0,cls4); cls3=fmaf(yz1,yz1,cls3); cls1=fmaf(yz2,yz2,cls1); \
                } \
            } \
        } \
        _Pragma("unroll") for (int v=0; v<4; ++v) { \
            if (vr && (S) >= 3 && (S) <= 14) { float h; \
                h=dy0[v]-DP[0][v]; cls3=fmaf(h,h,cls3); \
                h=dy1[v]-DP[1][v]; cls1=fmaf(h,h,cls1); \
                h=dz0[v]-DP[2][v]; cls3=fmaf(h,h,cls3); \
                h=dz1[v]-DP[3][v]; cls2=fmaf(h,h,cls2); \
                h=dz2[v]-DP[4][v]; cls1=fmaf(h,h,cls1); \
            } \
            DP[0][v]=dy0[v]; DP[1][v]=dy1[v]; DP[2][v]=dz0[v]; DP[3][v]=dz1[v]; DP[4][v]=dz2[v]; \
            if (vr && (S) >= 4) { float h = v0c[v]-2.f*V0a[v]+V0b[v]; cls1=fmaf(h,h,cls1); } \
            V0b[v]=V0a[v]; V0a[v]=v0c[v]; \
        } \
    } \
    if ((S) <= 14) { \
        float* Lw = lds + (((S)+1)%3)*SLC; \
        st4p(Lw+lof0, SBc[0]); st4p(Lw+lof1, SBc[1]); st4p(Lw+lof2, SBc[2]); \
        if (wv3) st4p(Lw+lof3, SBc[3]); \
    } \
}

__global__ __launch_bounds__(64)
void be_partials(const float* __restrict__ g, float* __restrict__ partial) {
    __shared__ float lds[3*SLC];   // 11.25 KB, private to this single wave

    const int tid = threadIdx.x;
    const int bid = blockIdx.x;
    const int is = bid % NSEG;
    int r1 = bid / NSEG;
    const int zt = r1 % 10; r1 /= 10;
    const int jt = r1 % 13;
    const int bb = r1 / 13;

    const int j0 = 2 + jt*12;            // output rows j0..j0+11 (stage j0-2..j0+13)
    const int wb = (zt < 9) ? 48*zt : 420;  // window float base (60 floats/row)
    const int i0 = 2 + is*IT;            // output slices i0..i0+11
    const float* __restrict__ Gs =
        g + (size_t)bb*SB + (size_t)(j0-2)*OY + wb + (size_t)(i0-2)*OX;

    // ---- staging: 240 f4/slice = 16 rows x 15; lane does 3 + masked 4th ----
    int gof0,gof1,gof2,gof3,lof0,lof1,lof2,lof3;
    { int f,row,pos;
      f=tid;     row=f/15; pos=f-15*row; gof0=row*OY+4*pos; lof0=row*RST+4*pos;
      f=tid+64;  row=f/15; pos=f-15*row; gof1=row*OY+4*pos; lof1=row*RST+4*pos;
      f=tid+128; row=f/15; pos=f-15*row; gof2=row*OY+4*pos; lof2=row*RST+4*pos;
      f=tid+192; row=f/15; pos=f-15*row; gof3=row*OY+4*pos; lof3=row*RST+4*pos; }
    const bool wv3 = tid < 48;
    if (!wv3) { gof3 = gof0; lof3 = lof0; }   // never used (masked)

    // ---- compute mapping: r = y-row (DPP row pos), Q = z-quad ----
    const int r = tid & 15;
    const int Q = tid >> 4;
    const int qmax = (zt == 9) ? 3 : 4;       // zt=9 covers out z 146..157
    const bool qact = Q < qmax;               // uniform per 16-lane DPP row
    const bool vr = (r >= 2) && (r <= 13);    // output rows
    const int oj = r*RST + 12*Q + ((zt == 9) ? 12 : 0);

    // x-pipeline state (parity banks A=even step, B=odd step)
    float4 sA[4], sB[4];
    float v0A0[4],v0A1[4],v0B0[4],v0B1[4];
    float dpA[5][4], dpB[5][4];
    #pragma unroll
    for (int v=0; v<4; ++v) {
        v0A0[v]=v0A1[v]=v0B0[v]=v0B1[v]=0.f;
        #pragma unroll
        for (int q=0; q<5; ++q) { dpA[q][v]=0.f; dpB[q][v]=0.f; }
    }
    float cls1=0.f, cls2=0.f, cls3=0.f, cls4=0.f;

    // prologue: slice 0 -> ring[0]; slice 1 -> bank sB
    { float4 a0=ld4p(Gs+gof0), a1=ld4p(Gs+gof1), a2=ld4p(Gs+gof2);
      st4p(lds+lof0,a0); st4p(lds+lof1,a1); st4p(lds+lof2,a2);
      if (wv3) { float4 a3=ld4p(Gs+gof3); st4p(lds+lof3,a3); } }
    { const float* bp = Gs + OX;
      sB[0]=ld4p(bp+gof0); sB[1]=ld4p(bp+gof1); sB[2]=ld4p(bp+gof2);
      if (wv3) sB[3]=ld4p(bp+gof3); }

    STEPX( 0, v0A0,v0A1,dpA, sB, sA)
    STEPX( 1, v0B0,v0B1,dpB, sA, sB)
    STEPX( 2, v0A0,v0A1,dpA, sB, sA)
    STEPX( 3, v0B0,v0B1,dpB, sA, sB)
    STEPX( 4, v0A0,v0A1,dpA, sB, sA)
    STEPX( 5, v0B0,v0B1,dpB, sA, sB)
    STEPX( 6, v0A0,v0A1,dpA, sB, sA)
    STEPX( 7, v0B0,v0B1,dpB, sA, sB)
    STEPX( 8, v0A0,v0A1,dpA, sB, sA)
    STEPX( 9, v0B0,v0B1,dpB, sA, sB)
    STEPX(10, v0A0,v0A1,dpA, sB, sA)
    STEPX(11, v0B0,v0B1,dpB, sA, sB)
    STEPX(12, v0A0,v0A1,dpA, sB, sA)
    STEPX(13, v0B0,v0B1,dpB, sA, sB)
    STEPX(14, v0A0,v0A1,dpA, sB, sA)
    STEPX(15, v0B0,v0B1,dpB, sA, sB)

    // fold weight classes (multiplicities 1,2,3,4; 0.0625 = (0.25)^2)
    float sv = fmaf(2.f, cls2, cls1);
    sv = fmaf(3.f, cls3, sv);
    sv = fmaf(4.f, cls4, sv);
    sv *= 0.0625f;

    #pragma unroll
    for (int off = 32; off > 0; off >>= 1) sv += __shfl_down(sv, off, 64);
    if (tid == 0) partial[bid] = sv;
}

__global__ __launch_bounds__(256)
void be_final(const float* __restrict__ partial, float* __restrict__ out) {
    float s = 0.0f;
    for (int i = threadIdx.x; i < NBLK; i += 256) s += partial[i];
    #pragma unroll
    for (int off = 32; off > 0; off >>= 1) s += __shfl_down(s, off, 64);
    __shared__ float ws[4];
    if ((threadIdx.x & 63) == 0) ws[threadIdx.x >> 6] = s;
    __syncthreads();
    if (threadIdx.x == 0)
        out[0] = ((ws[0] + ws[1]) + (ws[2] + ws[3])) * INV_SIZE;
}

extern "C" void kernel_launch(void* const* d_in, const int* in_sizes, int n_in,
                              void* d_out, int out_size, void* d_ws, size_t ws_size,
                              hipStream_t stream) {
    const float* grid = (const float*)d_in[0];
    float* out = (float*)d_out;
    float* partials = (float*)d_ws;    // 3380 floats

    be_partials<<<dim3(NBLK), dim3(64), 0, stream>>>(grid, partials);
    be_final<<<1, 256, 0, stream>>>(partials, out);
}